// Round 11
// baseline (39.885 us; speedup 1.0000x reference)
//
#include <hip/hip_runtime.h>
#include <hip/hip_bf16.h>

#define NQ 6
#define DIM 64
#define NLAYERS 6

typedef __attribute__((ext_vector_type(8))) short bf16x8;
typedef __attribute__((ext_vector_type(4))) float f32x4;

// ---------------------------------------------------------------------------
// Single fused kernel.
//   Phase A (per block): build the circuit matrix M = P*U5*...*P*U0*F
//     (complex 64x64) straight into LDS as single-plane bf16 MFMA fragments.
//     Wave wid owns columns k = 8*wid .. 8*wid+7; lane j carries M[j][k].
//     For these 8 columns, chunk=k>>5=wid>>2 and (k>>3)&3=wid&3 are uniform
//     and k&7=c8, so the 8 bf16 values pack into ONE bf16x8 -> one
//     ds_write_b128 per plane, landing in the exact frag image of R10:
//       frag f = (jt*2 + chunk)*2 + plane  (0=real, 1=imag)
//       ushort addr = f*512 + lane16*8 + e,  lane16=(j&15)+16*((k>>3)&3), e=k&7
//   Phase B: per-wave 16-row tile, y = M_bf16 * (xh + xl) via
//     mfma_f32_16x16x32_bf16 (M = A-operand from LDS, x = B-operand in regs),
//     out = (yr^2 + yi^2)/||x||^2, lane-resident inv, float4 epilogue.
// ---------------------------------------------------------------------------
__global__ __launch_bounds__(512, 4) void qenc_fused(const float* __restrict__ x,
                                                     const float* __restrict__ w,
                                                     float* __restrict__ out) {
    __shared__ __align__(16) unsigned short sB[8192];   // 16 KB frag image
    const int tid = threadIdx.x;
    const int lane = tid & 63;
    const int wid = tid >> 6;                 // 0..7
    const int row0 = blockIdx.x * 128 + wid * 16;
    const int r = lane & 15;      // batch row within tile
    const int g = lane >> 4;      // k-group

    // ---- issue x loads first (latency hides under the M-build chain)
    const float* xp = x + (size_t)(row0 + r) * DIM + 8 * g;
    float4 va = *(const float4*)(xp);
    float4 vb = *(const float4*)(xp + 4);
    float4 vc = *(const float4*)(xp + 32);
    float4 vd = *(const float4*)(xp + 36);

    // ================= Phase A: build M columns k = 8*wid + c8 =============
    const int j = lane;
    float vr[8], vi[8];
#pragma unroll
    for (int c8 = 0; c8 < 8; ++c8) {
        int k = wid * 8 + c8;
        int t = (j * k) & 63;
        float sv, cv;
        __sincosf((float)t * (3.14159265358979f / 32.0f), &sv, &cv); // exp(i*pi*t/32)
        vr[c8] = cv * 0.125f;
        vi[c8] = sv * 0.125f;
    }

    // CNOT-ring composite destination lane (push), same every layer
    int m = j;
#pragma unroll
    for (int q = 0; q < NQ; ++q) {
        int cb = 5 - q;
        int tb = 5 - ((q + 1) % NQ);
        if ((m >> cb) & 1) m ^= (1 << tb);
    }
    const int dst4 = m << 2;

#pragma unroll
    for (int l = 0; l < NLAYERS; ++l) {
        float cc[NQ], ss[NQ];
#pragma unroll
        for (int q = 0; q < NQ; ++q) {
            float th = w[l * NQ + q] * 0.5f;
            cc[q] = __cosf(th);
            ss[q] = __sinf(th);
        }
#pragma unroll
        for (int q = 0; q < NQ; ++q) {
            int b = 5 - q;
            float sgn = ((j >> b) & 1) ? ss[q] : -ss[q];
#pragma unroll
            for (int c8 = 0; c8 < 8; ++c8) {
                float pr = __shfl_xor(vr[c8], 1 << b);
                float pi = __shfl_xor(vi[c8], 1 << b);
                vr[c8] = cc[q] * vr[c8] + sgn * pr;
                vi[c8] = cc[q] * vi[c8] + sgn * pi;
            }
        }
#pragma unroll
        for (int c8 = 0; c8 < 8; ++c8) {
            vr[c8] = __int_as_float(__builtin_amdgcn_ds_permute(dst4, __float_as_int(vr[c8])));
            vi[c8] = __int_as_float(__builtin_amdgcn_ds_permute(dst4, __float_as_int(vi[c8])));
        }
    }

    // pack 8 columns -> one bf16x8 per plane, single ds_write_b128 each
    bf16x8 regR, regI;
#pragma unroll
    for (int c8 = 0; c8 < 8; ++c8) {
        __hip_bfloat16 rh = __float2bfloat16(vr[c8]);
        __hip_bfloat16 ih = __float2bfloat16(vi[c8]);
        regR[c8] = *(short*)&rh;
        regI[c8] = *(short*)&ih;
    }
    {
        const int jt = j >> 4;
        const int fbase = ((jt * 2 + (wid >> 2)) * 2) * 512 + ((j & 15) + 16 * (wid & 3)) * 8;
        *(bf16x8*)(sB + fbase)       = regR;
        *(bf16x8*)(sB + fbase + 512) = regI;
    }

    // ================= Phase B: per-row normalize + MFMA ====================
    float xf[16];
    *(float4*)(xf)      = va;  *(float4*)(xf + 4)  = vb;
    *(float4*)(xf + 8)  = vc;  *(float4*)(xf + 12) = vd;

    // norm (reduce over the 4 lanes sharing row r)
    float n0 = 0.f;
#pragma unroll
    for (int i = 0; i < 16; ++i) n0 = fmaf(xf[i], xf[i], n0);
    n0 += __shfl_xor(n0, 16);
    n0 += __shfl_xor(n0, 32);
    const float inv = 1.0f / n0;

    // hi/lo bf16 x-fragments (chunk c: k = 32c + 8g .. +7)
    bf16x8 xh[2], xl[2];
#pragma unroll
    for (int c = 0; c < 2; ++c)
#pragma unroll
        for (int i = 0; i < 8; ++i) {
            float f = xf[c * 8 + i];
            __hip_bfloat16 hh = __float2bfloat16(f);
            __hip_bfloat16 ll = __float2bfloat16(f - __bfloat162float(hh));
            xh[c][i] = *(short*)&hh;
            xl[c][i] = *(short*)&ll;
        }

    __syncthreads();   // M image complete

    const f32x4 z = {0.f, 0.f, 0.f, 0.f};
    f32x4 acr[4] = {z, z, z, z};
    f32x4 aci[4] = {z, z, z, z};
    const unsigned short* bp = sB + lane * 8;

#pragma unroll
    for (int jt = 0; jt < 4; ++jt) {
#pragma unroll
        for (int c = 0; c < 2; ++c) {
            const unsigned short* fb = bp + ((jt * 2 + c) * 2) * 512;
            bf16x8 mr = *(const bf16x8*)(fb);
            bf16x8 mi = *(const bf16x8*)(fb + 512);
            acr[jt] = __builtin_amdgcn_mfma_f32_16x16x32_bf16(mr, xh[c], acr[jt], 0, 0, 0);
            acr[jt] = __builtin_amdgcn_mfma_f32_16x16x32_bf16(mr, xl[c], acr[jt], 0, 0, 0);
            aci[jt] = __builtin_amdgcn_mfma_f32_16x16x32_bf16(mi, xh[c], aci[jt], 0, 0, 0);
            aci[jt] = __builtin_amdgcn_mfma_f32_16x16x32_bf16(mi, xl[c], aci[jt], 0, 0, 0);
        }
    }

    // epilogue: lane holds out[row0+r][jt*16 + 4g + v], v=0..3
    float* op = out + (size_t)(row0 + r) * DIM + 4 * g;
#pragma unroll
    for (int jt = 0; jt < 4; ++jt) {
        float4 o;
        o.x = (acr[jt][0] * acr[jt][0] + aci[jt][0] * aci[jt][0]) * inv;
        o.y = (acr[jt][1] * acr[jt][1] + aci[jt][1] * aci[jt][1]) * inv;
        o.z = (acr[jt][2] * acr[jt][2] + aci[jt][2] * aci[jt][2]) * inv;
        o.w = (acr[jt][3] * acr[jt][3] + aci[jt][3] * aci[jt][3]) * inv;
        *(float4*)(op + jt * 16) = o;
    }
}

extern "C" void kernel_launch(void* const* d_in, const int* in_sizes, int n_in,
                              void* d_out, int out_size, void* d_ws, size_t ws_size,
                              hipStream_t stream) {
    const float* x = (const float*)d_in[0];
    const float* w = (const float*)d_in[1];
    float* out = (float*)d_out;
    int B = in_sizes[0] / DIM;

    hipLaunchKernelGGL(qenc_fused, dim3(B / 128), dim3(512), 0, stream, x, w, out);
}

// Round 13
// 16.806 us; speedup vs baseline: 2.3733x; 2.3733x over previous
//
#include <hip/hip_runtime.h>
#include <hip/hip_bf16.h>

#define NQ 6
#define DIM 64
#define NLAYERS 6

typedef __attribute__((ext_vector_type(8))) short bf16x8;
typedef __attribute__((ext_vector_type(4))) float f32x4;

// async global->LDS copy, 16B per lane, linear (dest = wave-uniform base + lane*16)
#define GLOAD_LDS16(gp, lp) \
    __builtin_amdgcn_global_load_lds((const __attribute__((address_space(1))) void*)(gp), \
                                     (__attribute__((address_space(3))) void*)(lp), 16, 0, 0)

// ---------------------------------------------------------------------------
// build_M: fused circuit matrix M = P*U5*...*P*U0*F (complex 64x64), emitted
// as MFMA fragments, single bf16 plane per component:
//   frag f = (jt*2 + chunk)*2 + plane  (0 = real, 1 = imag)
//   ushort addr = f*512 + lane16*8 + e          (16 KB total image)
//   lane16 = (j&15) + 16*((k>>3)&3), chunk = k>>5, e = k&7, jt = j>>4.
// HW trig (v_sin/v_cos); M bf16-rounding -> ~2e-4 on probs (validated R10).
// ---------------------------------------------------------------------------
__global__ __launch_bounds__(64) void build_M(const float* __restrict__ w,
                                              unsigned short* __restrict__ Bf) {
    const int k = blockIdx.x;    // column 0..63
    const int j = threadIdx.x;   // row/lane 0..63

    int t = (j * k) & 63;
    float sv, cv;
    __sincosf((float)t * (3.14159265358979f / 32.0f), &sv, &cv);  // exp(i*pi*t/32)
    float vr = cv * 0.125f;
    float vi = sv * 0.125f;

    int m = j;
#pragma unroll
    for (int q = 0; q < NQ; ++q) {
        int cb = 5 - q;
        int tb = 5 - ((q + 1) % NQ);
        if ((m >> cb) & 1) m ^= (1 << tb);
    }
    const int dst4 = m << 2;

#pragma unroll
    for (int l = 0; l < NLAYERS; ++l) {
#pragma unroll
        for (int q = 0; q < NQ; ++q) {
            float th = w[l * NQ + q] * 0.5f;
            float c = __cosf(th), s = __sinf(th);
            int b = 5 - q;
            float pr = __shfl_xor(vr, 1 << b);
            float pi = __shfl_xor(vi, 1 << b);
            float sgn = ((j >> b) & 1) ? s : -s;
            vr = c * vr + sgn * pr;
            vi = c * vi + sgn * pi;
        }
        vr = __int_as_float(__builtin_amdgcn_ds_permute(dst4, __float_as_int(vr)));
        vi = __int_as_float(__builtin_amdgcn_ds_permute(dst4, __float_as_int(vi)));
    }

    const int jt = j >> 4;
    const int lane16 = (j & 15) + 16 * ((k >> 3) & 3);
    const int chunk = k >> 5;
    const int e = k & 7;
    const int base = ((jt * 2 + chunk) * 2) * 512 + lane16 * 8 + e;

    __hip_bfloat16 rh = __float2bfloat16(vr);
    __hip_bfloat16 ih = __float2bfloat16(vi);
    Bf[base]       = *(unsigned short*)&rh;
    Bf[base + 512] = *(unsigned short*)&ih;
}

// ---------------------------------------------------------------------------
// qenc_main: ONE block per CU. 1024 threads = 16 waves; each wave a 16-row
// tile, 256 rows/block, grid 256. M image (16 KB) staged once per CU via one
// global_load_lds per thread. Single-plane bf16 M (A-operand), 2-term x
// split (B-operand). Lane-resident inv; nontemporal f32x4 epilogue.
// ---------------------------------------------------------------------------
__global__ __launch_bounds__(1024) void qenc_main(const float* __restrict__ x,
                                                  const unsigned short* __restrict__ Bf,
                                                  float* __restrict__ out) {
    __shared__ __align__(16) unsigned short sB[8192];   // 16 KB
    const int tid = threadIdx.x;
    const int lane = tid & 63;
    const int wid = tid >> 6;                 // 0..15
    const int row0 = blockIdx.x * 256 + wid * 16;
    const int r = lane & 15;      // batch row within tile (B-side n index)
    const int g = lane >> 4;      // k-group

    // ---- issue x loads first (latency hides under stage + barrier)
    const float* xp = x + (size_t)(row0 + r) * DIM + 8 * g;
    float4 va = *(const float4*)(xp);
    float4 vb = *(const float4*)(xp + 4);
    float4 vc = *(const float4*)(xp + 32);
    float4 vd = *(const float4*)(xp + 36);

    // ---- async stage M fragments to LDS: 1 x 16B per thread, linear
    GLOAD_LDS16(Bf + (size_t)tid * 8, sB + (size_t)tid * 8);

    float xf[16];
    *(float4*)(xf)      = va;  *(float4*)(xf + 4)  = vb;
    *(float4*)(xf + 8)  = vc;  *(float4*)(xf + 12) = vd;

    // ---- norm (reduce over the 4 lanes sharing row r)
    float n0 = 0.f;
#pragma unroll
    for (int i = 0; i < 16; ++i) n0 = fmaf(xf[i], xf[i], n0);
    n0 += __shfl_xor(n0, 16);
    n0 += __shfl_xor(n0, 32);
    const float inv = 1.0f / n0;

    // ---- hi/lo bf16 x-fragments (chunk c: k = 32c + 8g .. +7)
    bf16x8 xh[2], xl[2];
#pragma unroll
    for (int c = 0; c < 2; ++c)
#pragma unroll
        for (int i = 0; i < 8; ++i) {
            float f = xf[c * 8 + i];
            __hip_bfloat16 hh = __float2bfloat16(f);
            __hip_bfloat16 ll = __float2bfloat16(f - __bfloat162float(hh));
            xh[c][i] = *(short*)&hh;
            xl[c][i] = *(short*)&ll;
        }

    __syncthreads();   // drains vmcnt(0): staged LDS ready

    // ---- MFMA main loop: A = M fragment (LDS, single plane), B = x hi/lo
    const f32x4 z = {0.f, 0.f, 0.f, 0.f};
    f32x4 acr[4] = {z, z, z, z};
    f32x4 aci[4] = {z, z, z, z};
    const unsigned short* bp = sB + lane * 8;

#pragma unroll
    for (int jt = 0; jt < 4; ++jt) {
#pragma unroll
        for (int c = 0; c < 2; ++c) {
            const unsigned short* fb = bp + ((jt * 2 + c) * 2) * 512;
            bf16x8 mr = *(const bf16x8*)(fb);
            bf16x8 mi = *(const bf16x8*)(fb + 512);
            acr[jt] = __builtin_amdgcn_mfma_f32_16x16x32_bf16(mr, xh[c], acr[jt], 0, 0, 0);
            acr[jt] = __builtin_amdgcn_mfma_f32_16x16x32_bf16(mr, xl[c], acr[jt], 0, 0, 0);
            aci[jt] = __builtin_amdgcn_mfma_f32_16x16x32_bf16(mi, xh[c], aci[jt], 0, 0, 0);
            aci[jt] = __builtin_amdgcn_mfma_f32_16x16x32_bf16(mi, xl[c], aci[jt], 0, 0, 0);
        }
    }

    // ---- epilogue: lane holds out[row0+r][jt*16 + 4g + v], v=0..3
    float* op = out + (size_t)(row0 + r) * DIM + 4 * g;
#pragma unroll
    for (int jt = 0; jt < 4; ++jt) {
        f32x4 o;
        o[0] = (acr[jt][0] * acr[jt][0] + aci[jt][0] * aci[jt][0]) * inv;
        o[1] = (acr[jt][1] * acr[jt][1] + aci[jt][1] * aci[jt][1]) * inv;
        o[2] = (acr[jt][2] * acr[jt][2] + aci[jt][2] * aci[jt][2]) * inv;
        o[3] = (acr[jt][3] * acr[jt][3] + aci[jt][3] * aci[jt][3]) * inv;
        __builtin_nontemporal_store(o, (f32x4*)(op + jt * 16));
    }
}

extern "C" void kernel_launch(void* const* d_in, const int* in_sizes, int n_in,
                              void* d_out, int out_size, void* d_ws, size_t ws_size,
                              hipStream_t stream) {
    const float* x = (const float*)d_in[0];
    const float* w = (const float*)d_in[1];
    float* out = (float*)d_out;
    unsigned short* Bf = (unsigned short*)d_ws;   // 16 KB fragment image
    int B = in_sizes[0] / DIM;

    hipLaunchKernelGGL(build_M, dim3(DIM), dim3(64), 0, stream, w, Bf);
    hipLaunchKernelGGL(qenc_main, dim3(B / 256), dim3(1024), 0, stream, x, Bf, out);
}